// Round 15
// baseline (138.915 us; speedup 1.0000x reference)
//
#include <hip/hip_runtime.h>

#define HH_ 128
#define WW_ 128
#define LL_ (HH_*WW_)     // 16384
#define NH 8
#define DHD 12
#define KD 256
#define BB_ 2
#define NROW (BB_*LL_)    // 32768
#define PW 146            // padded width/height for a1 (halo 9)
#define PPB (PW*PW)       // 21316 pixels per batch

typedef __attribute__((ext_vector_type(8))) short short8v;
typedef __attribute__((ext_vector_type(4))) float f32x4;
typedef unsigned short ushortT;

__device__ __forceinline__ float4 ld4(const float* p) {
    return *reinterpret_cast<const float4*>(p);
}
__device__ __forceinline__ unsigned int pk2(float a, float b) {
    unsigned int ua = __float_as_uint(a);
    unsigned int ub = __float_as_uint(b);
    ua = (ua + 0x7FFFu + ((ua >> 16) & 1u)) >> 16;
    ub = (ub + 0x7FFFu + ((ub >> 16) & 1u)) >> 16;
    return ua | (ub << 16);
}
__device__ __forceinline__ ushortT bf1(float a) {
    unsigned int u = __float_as_uint(a);
    return (ushortT)((u + 0x7FFFu + ((u >> 16) & 1u)) >> 16);
}
__device__ __forceinline__ float ubf(ushortT v) {
    return __uint_as_float(((unsigned int)v) << 16);
}
// single-instruction packed f32->bf16 (RNE), gfx950
__device__ __forceinline__ unsigned int cvtpk(float a, float b) {
    unsigned int r;
    asm("v_cvt_pk_bf16_f32 %0, %1, %2" : "=v"(r) : "v"(a), "v"(b));
    return r;
}

// ======= K_FRONT: [0,1024) dw5 branchless -> padded a1p interior;
//   [1024,2048) E->ET16; [2048,2228) weight prep; [2228,2268) a1p halo zero =======
__global__ __launch_bounds__(256, 4) void k_front(const float* __restrict__ x,
        const float* __restrict__ c0w, const float* __restrict__ c0b,
        const float* __restrict__ E, const float* __restrict__ Wq,
        const float* __restrict__ W0, const float* __restrict__ w1,
        float* __restrict__ a1p, ushortT* __restrict__ ET,
        ushortT* __restrict__ wqT, ushortT* __restrict__ w0T,
        ushortT* __restrict__ w1c) {
    __shared__ __align__(16) float shf[2400];   // 9600B union
    const int tid = threadIdx.x;
    if (blockIdx.x < 1024) {
        // ---- dw5: depthwise 5x5 pad 2, branchless (clamp + weight mask) ----
        float* wl = shf;   // [25][96]
        for (int i = tid; i < 25*96; i += 256) {
            int c = i / 25, t = i % 25;
            wl[t*96 + c] = c0w[i];
        }
        __syncthreads();
        const int c4 = (tid & 7)*4;
        const int px = tid >> 3;
        const int pix0 = blockIdx.x * 32;
        const int b = pix0 >> 14;
        const int y = (pix0 & 16383) >> 7;
        const int xx = (pix0 & 127) + px;
        float4 acc[3];
#pragma unroll
        for (int ch = 0; ch < 3; ++ch) { acc[ch].x=0.f; acc[ch].y=0.f; acc[ch].z=0.f; acc[ch].w=0.f; }
#pragma unroll
        for (int iy = 0; iy < 5; ++iy) {
            int y2 = y + iy - 2;
            int y2c = min(max(y2, 0), 127);
            float fy = ((unsigned)y2 < 128u) ? 1.f : 0.f;
            float4 xv[5][3];
#pragma unroll
            for (int ix = 0; ix < 5; ++ix) {
                int x2 = xx + ix - 2;
                int x2c = min(max(x2, 0), 127);
                const float* src = x + ((b << 14) + y2c*WW_ + x2c)*96 + c4;
#pragma unroll
                for (int ch = 0; ch < 3; ++ch) xv[ix][ch] = ld4(src + ch*32);
            }
#pragma unroll
            for (int ix = 0; ix < 5; ++ix) {
                int x2 = xx + ix - 2;
                float f = fy * (((unsigned)x2 < 128u) ? 1.f : 0.f);
                const float* wt = &wl[(iy*5 + ix)*96 + c4];
#pragma unroll
                for (int ch = 0; ch < 3; ++ch) {
                    float4 wv = ld4(wt + ch*32);
                    wv.x *= f; wv.y *= f; wv.z *= f; wv.w *= f;
                    acc[ch].x = fmaf(xv[ix][ch].x, wv.x, acc[ch].x);
                    acc[ch].y = fmaf(xv[ix][ch].y, wv.y, acc[ch].y);
                    acc[ch].z = fmaf(xv[ix][ch].z, wv.z, acc[ch].z);
                    acc[ch].w = fmaf(xv[ix][ch].w, wv.w, acc[ch].w);
                }
            }
        }
        float* dst = a1p + ((long)b*PPB + (y + 9)*PW + xx + 9)*96;
#pragma unroll
        for (int ch = 0; ch < 3; ++ch) {
            float4 bv = ld4(c0b + ch*32 + c4);
            float4 r;
            r.x = acc[ch].x + bv.x; r.y = acc[ch].y + bv.y;
            r.z = acc[ch].z + bv.z; r.w = acc[ch].w + bv.w;
            *reinterpret_cast<float4*>(dst + ch*32 + c4) = r;
        }
    } else if (blockIdx.x < 2048) {
        // ---- E -> ET16[kk][j] bf16 transposed ----
        ushortT* Tz = (ushortT*)shf;   // [64][66]
        const int bid = blockIdx.x - 1024;
        const int jt = bid >> 2, kt = bid & 3;
        const int j0 = jt * 64, kk0 = kt * 64;
        for (int i = tid; i < 64*16; i += 256) {
            int row = i >> 4, s4 = (i & 15) << 2;
            float4 e4 = ld4(&E[(long)(j0 + row)*256 + kk0 + s4]);
            Tz[(s4 + 0)*66 + row] = bf1(e4.x);
            Tz[(s4 + 1)*66 + row] = bf1(e4.y);
            Tz[(s4 + 2)*66 + row] = bf1(e4.z);
            Tz[(s4 + 3)*66 + row] = bf1(e4.w);
        }
        __syncthreads();
        unsigned int* Tu = (unsigned int*)Tz;
        for (int i = tid; i < 64*32; i += 256) {
            int kk = i >> 5, s = i & 31;
            ((unsigned int*)ET)[(((long)(kk0 + kk) << 14) + j0 >> 1) + s] = Tu[kk*33 + s];
        }
    } else if (blockIdx.x < 2228) {
        int i = (blockIdx.x - 2048)*256 + tid;
        if (i < 27648) {
            int n = i / 96, k = i % 96;
            wqT[n*96 + k] = bf1(Wq[k*288 + n]);
        } else if (i < 36864) {
            int j = i - 27648;
            int n = j / 96, k = j % 96;
            w0T[n*96 + k] = bf1(W0[k*96 + n]);
        } else if (i < 46080) {
            int j = i - 36864;
            w1c[j] = bf1(w1[j]);
        }
    } else {
        // ---- zero a1p halo: 9864 halo pixels x 96 floats ----
        int gid = (blockIdx.x - 2228)*256 + tid;
        if (gid < 9864) {
            int bb = gid / 4932, hp = gid % 4932;
            int y, xp;
            if (hp < 1314)      { y = hp / 146;              xp = hp % 146; }
            else if (hp < 2628) { int h2 = hp - 1314; y = 137 + h2/146; xp = h2 % 146; }
            else if (hp < 3780) { int h2 = hp - 2628; y = 9 + h2/9;     xp = h2 % 9; }
            else                { int h2 = hp - 3780; y = 9 + h2/9;     xp = 137 + h2 % 9; }
            float4* p = (float4*)(a1p + ((long)bb*PPB + y*PW + xp)*96);
#pragma unroll
            for (int t = 0; t < 24; ++t) p[t] = (float4){0.f, 0.f, 0.f, 0.f};
        }
    }
}

// ======= K_MID: [0,512) qkv MFMA; [512,1536) dw7 on padded a1p (no bounds checks) =======
__global__ __launch_bounds__(256, 4) void k_mid(const float* __restrict__ x,
        const ushortT* __restrict__ wqT, ushortT* __restrict__ qkv16,
        const float* __restrict__ a1p, const float* __restrict__ cspw,
        const float* __restrict__ cspb, ushortT* __restrict__ a2_16) {
    __shared__ __align__(16) float shm[4704];   // 18816B union
    const int tid = threadIdx.x;
    if (blockIdx.x < 512) {
        // ---- qkv16 = bf16(x @ Wqkv) via MFMA ----
        ushortT* xb = (ushortT*)shm;   // [64][104]
        const int r0w = blockIdx.x * 64;
        for (int i = tid; i < 64*48; i += 256) {
            int r = i / 48, cp = i % 48;
            const float* sp = x + (long)(r0w + r)*96 + cp*2;
            ((unsigned int*)xb)[r*52 + cp] = pk2(sp[0], sp[1]);
        }
        __syncthreads();
        const int lane = tid & 63, wv = tid >> 6;
        const int l15 = lane & 15, l4 = lane >> 4;
        short8v bx[3];
#pragma unroll
        for (int kt = 0; kt < 3; ++kt)
            bx[kt] = *(const short8v*)((const short*)xb + (wv*16 + l15)*104 + kt*32 + l4*8);
#pragma unroll 2
        for (int mt = 0; mt < 18; ++mt) {
            f32x4 acc = {0.f, 0.f, 0.f, 0.f};
#pragma unroll
            for (int kt = 0; kt < 3; ++kt) {
                short8v a = *(const short8v*)((const short*)wqT + (mt*16 + l15)*96 + kt*32 + l4*8);
                acc = __builtin_amdgcn_mfma_f32_16x16x32_bf16(a, bx[kt], acc, 0, 0, 0);
            }
            unsigned int* q32 = (unsigned int*)(qkv16 + (long)(r0w + wv*16 + l15)*288 + mt*16 + l4*4);
            q32[0] = pk2(acc[0], acc[1]);
            q32[1] = pk2(acc[2], acc[3]);
        }
    } else {
        // ---- dw7: 7x7 dil3, fully unconditional taps on padded a1p ----
        float* wl = shm;   // [49][96]
        for (int i = tid; i < 49*96; i += 256) {
            int c = i / 49, t = i % 49;
            wl[t*96 + c] = cspw[i];
        }
        __syncthreads();
        const int c4 = (tid & 7)*4;
        const int px = tid >> 3;
        const int pix0 = (blockIdx.x - 512) * 32;
        const int b = pix0 >> 14;
        const int y = (pix0 & 16383) >> 7;
        const int xx = (pix0 & 127) + px;
        const float* base = a1p + ((long)b*PPB + y*PW + xx)*96 + c4;
        float4 acc[3];
#pragma unroll
        for (int ch = 0; ch < 3; ++ch) { acc[ch].x=0.f; acc[ch].y=0.f; acc[ch].z=0.f; acc[ch].w=0.f; }
#pragma unroll
        for (int iy = 0; iy < 7; ++iy) {
            const float* rp = base + iy*3*PW*96;
            float4 xv[7][3];
#pragma unroll
            for (int ix = 0; ix < 7; ++ix)
#pragma unroll
                for (int ch = 0; ch < 3; ++ch)
                    xv[ix][ch] = ld4(rp + ix*3*96 + ch*32);
#pragma unroll
            for (int ix = 0; ix < 7; ++ix) {
                const float* wt = &wl[(iy*7 + ix)*96 + c4];
#pragma unroll
                for (int ch = 0; ch < 3; ++ch) {
                    float4 wv = ld4(wt + ch*32);
                    acc[ch].x = fmaf(xv[ix][ch].x, wv.x, acc[ch].x);
                    acc[ch].y = fmaf(xv[ix][ch].y, wv.y, acc[ch].y);
                    acc[ch].z = fmaf(xv[ix][ch].z, wv.z, acc[ch].z);
                    acc[ch].w = fmaf(xv[ix][ch].w, wv.w, acc[ch].w);
                }
            }
        }
        ushortT* dst = a2_16 + (long)(pix0 + px)*96;
#pragma unroll
        for (int ch = 0; ch < 3; ++ch) {
            float4 bv = ld4(cspb + ch*32 + c4);
            unsigned int* d32 = (unsigned int*)(dst + ch*32 + c4);
            d32[0] = pk2(acc[ch].x + bv.x, acc[ch].y + bv.y);
            d32[1] = pk2(acc[ch].z + bv.z, acc[ch].w + bv.w);
        }
    }
}

// ------- K2c: fused a3 = a2@w1^T + b1 (MFMA); vf = x*a3*v; writes BOTH halves
// of XT[b][cc 192][j] (cc<96 = k transposed, cc>=96 = vf transposed). 64 rows/blk -------
__global__ __launch_bounds__(256) void k_pw_gate(const ushortT* __restrict__ a2_16,
        const ushortT* __restrict__ w1c, const float* __restrict__ b1,
        const float* __restrict__ xin, const ushortT* __restrict__ qkv16,
        ushortT* __restrict__ XT) {
    __shared__ ushortT ab[64*104];     // 13312B
    __shared__ ushortT ktile[96*66];   // 12672B
    __shared__ ushortT vtile[96*66];   // 12672B
    const int tid = threadIdx.x;
    const int r0 = blockIdx.x * 64;
    const int b = r0 >> 14, j0 = r0 & 16383;
    const unsigned int* a2u = (const unsigned int*)a2_16;
    for (int i = tid; i < 64*48; i += 256) {
        int r = i / 48, cp = i % 48;
        ((unsigned int*)ab)[r*52 + cp] = a2u[(long)(r0 + r)*48 + cp];
    }
    const unsigned int* q32 = (const unsigned int*)qkv16;
    for (int i = tid; i < 64*48; i += 256) {
        int row = i / 48, cp = i % 48;
        unsigned int kk2 = q32[(long)(r0 + row)*144 + 48 + cp];
        ktile[(2*cp + 0)*66 + row] = (ushortT)(kk2 & 0xFFFF);
        ktile[(2*cp + 1)*66 + row] = (ushortT)(kk2 >> 16);
    }
    __syncthreads();
    const int lane = tid & 63, wv = tid >> 6;
    const int l15 = lane & 15, l4 = lane >> 4;
    const int row = r0 + wv*16 + l15;
    const int jloc = wv*16 + l15;
    short8v bx[3];
#pragma unroll
    for (int kt = 0; kt < 3; ++kt)
        bx[kt] = *(const short8v*)((const short*)ab + (wv*16 + l15)*104 + kt*32 + l4*8);
#pragma unroll
    for (int mt = 0; mt < 6; ++mt) {
        f32x4 acc = {0.f, 0.f, 0.f, 0.f};
#pragma unroll
        for (int kt = 0; kt < 3; ++kt) {
            short8v a = *(const short8v*)((const short*)w1c + (mt*16 + l15)*96 + kt*32 + l4*8);
            acc = __builtin_amdgcn_mfma_f32_16x16x32_bf16(a, bx[kt], acc, 0, 0, 0);
        }
        const int c0 = mt*16 + l4*4;
        float4 b4 = ld4(&b1[c0]);
        float4 x4 = ld4(&xin[(long)row*96 + c0]);
        uint2 vv = *reinterpret_cast<const uint2*>(qkv16 + (long)row*288 + 192 + c0);
        float v0 = ubf((ushortT)(vv.x & 0xFFFF)), v1 = ubf((ushortT)(vv.x >> 16));
        float v2 = ubf((ushortT)(vv.y & 0xFFFF)), v3 = ubf((ushortT)(vv.y >> 16));
        vtile[(c0 + 0)*66 + jloc] = bf1(x4.x * v0 * (acc[0] + b4.x));
        vtile[(c0 + 1)*66 + jloc] = bf1(x4.y * v1 * (acc[1] + b4.y));
        vtile[(c0 + 2)*66 + jloc] = bf1(x4.z * v2 * (acc[2] + b4.z));
        vtile[(c0 + 3)*66 + jloc] = bf1(x4.w * v3 * (acc[3] + b4.w));
    }
    __syncthreads();
    unsigned int* XTu = (unsigned int*)XT;
    unsigned int* ku = (unsigned int*)ktile;
    unsigned int* vu = (unsigned int*)vtile;
    for (int i = tid; i < 96*32; i += 256) {
        int cc = i >> 5, s = i & 31;
        XTu[((((long)b*192 + cc) << 14) + j0 >> 1) + s] = ku[cc*33 + s];
    }
    for (int i = tid; i < 96*32; i += 256) {
        int cc = i >> 5, s = i & 31;
        XTu[((((long)b*192 + 96 + cc) << 14) + j0 >> 1) + s] = vu[cc*33 + s];
    }
}

// ------- K3a: E-reduction as MFMA split-K GEMM (no LDS) -------
__global__ __launch_bounds__(512, 2) void k_ered(const ushortT* __restrict__ ET,
        const ushortT* __restrict__ XT, ushortT* __restrict__ part16) {
    const int tid = threadIdx.x;
    const int lane = tid & 63, wv = tid >> 6;
    const int l15 = lane & 15, l4 = lane >> 4;
    const int mtg = wv & 3, nth = wv >> 2;
    const int b  = blockIdx.x >> 7;
    const int jc = blockIdx.x & 127;
    const int j0 = jc * 128;
    f32x4 acc[4][6];
#pragma unroll
    for (int mi = 0; mi < 4; ++mi)
#pragma unroll
        for (int ni = 0; ni < 6; ++ni)
            acc[mi][ni] = (f32x4){0.f, 0.f, 0.f, 0.f};
    const ushortT* Ab = ET + ((long)(mtg*64 + l15) << 14) + j0 + l4*8;
    const ushortT* Bb = XT + (((long)b*192 + nth*96 + l15) << 14) + j0 + l4*8;
#pragma unroll
    for (int ks = 0; ks < 4; ++ks) {
        short8v a[4], bx[6];
#pragma unroll
        for (int mi = 0; mi < 4; ++mi)
            a[mi] = *(const short8v*)(Ab + ((long)mi << 18) + ks*32);
#pragma unroll
        for (int ni = 0; ni < 6; ++ni)
            bx[ni] = *(const short8v*)(Bb + ((long)ni << 18) + ks*32);
#pragma unroll
        for (int mi = 0; mi < 4; ++mi)
#pragma unroll
            for (int ni = 0; ni < 6; ++ni)
                acc[mi][ni] = __builtin_amdgcn_mfma_f32_16x16x32_bf16(a[mi], bx[ni], acc[mi][ni], 0, 0, 0);
    }
    const long base = (long)(b*128 + jc)*49152;
#pragma unroll
    for (int mi = 0; mi < 4; ++mi) {
        int kkb = (mtg*4 + mi)*16 + l4*4;
#pragma unroll
        for (int ni = 0; ni < 6; ++ni) {
            int cc = (nth*6 + ni)*16 + l15;
#pragma unroll
            for (int r = 0; r < 4; ++r)
                part16[base + (long)(kkb + r)*192 + cc] = bf1(acc[mi][ni][r]);
        }
    }
}

// ------- K3b: reduce partials -> bf16 kp16[b][h][kk][16] (scaled by 1/sqrt(12)*log2e,
// pads 0), vp16[b][h][16][256] (row 12 = ONES for MFMA row-sum, 13..15 = 0) -------
__global__ __launch_bounds__(256) void k_ered_fin(const ushortT* __restrict__ part16,
        ushortT* __restrict__ kp16, ushortT* __restrict__ vp16) {
    const int idx = blockIdx.x*256 + threadIdx.x;  // 2*2*256*96 = 98304
    const int c  = idx % 96;
    const int kk = (idx / 96) % 256;
    const int m  = (idx / (96*256)) % 2;
    const int b  = idx / (96*256*2);
    float s = 0.f;
    long off = ((long)(b*128)*256 + kk)*192 + m*96 + c;
    for (int jc = 0; jc < 128; ++jc) {
        s += ubf(part16[off]);
        off += 49152;
    }
    const int h = c / DHD, d = c % DHD;
    if (m == 0) {
        kp16[((b*NH + h)*256 + kk)*16 + d] = bf1(s * 0.4164701998f);
        if (d < 4) kp16[((b*NH + h)*256 + kk)*16 + 12 + d] = 0;
    } else {
        vp16[((b*NH + h)*16 + d)*256 + kk] = bf1(s);
        if (d < 4)
            vp16[((b*NH + h)*16 + 12 + d)*256 + kk] = (d == 0) ? (ushortT)0x3F80 : (ushortT)0;
    }
}

// ------- K4 v3: flash-style. Block = 64 rows x ONE head; kp/vp staged in LDS -------
__global__ __launch_bounds__(256, 4) void k_attn(const ushortT* __restrict__ qkv16,
        const ushortT* __restrict__ kp16, const ushortT* __restrict__ vp16,
        ushortT* __restrict__ obuf) {
    __shared__ ushortT lds[24720];
    const int tid = threadIdx.x;
    const int lane = tid & 63, wv = tid >> 6;
    const int l15 = lane & 15, l4 = lane >> 4;
    const int bid = blockIdx.x;
    const int r0 = (bid >> 3) * 64;
    const int h = bid & 7;
    const int b = r0 >> 14;
    {
        const uint4* ksrc = (const uint4*)(kp16 + ((long)(b*NH + h) << 12));
        uint4* kdst = (uint4*)lds;
        kdst[tid] = ksrc[tid];
        kdst[256 + tid] = ksrc[256 + tid];
        const uint4* vsrc = (const uint4*)(vp16 + ((long)(b*NH + h) << 12));
        uint4* vdst = (uint4*)(lds + 4112);
        int r1 = tid >> 5, s1 = tid & 31;
        vdst[r1*33 + s1] = vsrc[tid];
        int j2 = tid + 256;
        int r2 = j2 >> 5, s2 = j2 & 31;
        vdst[r2*33 + s2] = vsrc[j2];
        if (tid < 2) ((uint4*)(lds + 4096))[tid] = (uint4){0u, 0u, 0u, 0u};
    }
    __syncthreads();
    ushortT* Pw = lds + 8336 + wv*4096;
    unsigned int* Pu = (unsigned int*)Pw;
    const int wbase = (l4 >> 1)*64 + l15*4 + (l4 & 1)*2;
    const f32x4 z = {0.f, 0.f, 0.f, 0.f};
    const int row0 = r0 + wv*16;
    short8v bq = {0, 0, 0, 0, 0, 0, 0, 0};
    {
        unsigned int* bq32 = (unsigned int*)&bq;
        const ushortT* qp = qkv16 + (long)(row0 + l15)*288 + h*12;
        if (l4 == 0) {
            uint2 t0 = *reinterpret_cast<const uint2*>(qp);
            uint2 t1 = *reinterpret_cast<const uint2*>(qp + 4);
            bq32[0] = t0.x; bq32[1] = t0.y; bq32[2] = t1.x; bq32[3] = t1.y;
        } else if (l4 == 1) {
            uint2 t0 = *reinterpret_cast<const uint2*>(qp + 8);
            bq32[0] = t0.x; bq32[1] = t0.y;
        }
    }
    const ushortT* kpl = lds + l15*16 + l4*8;
#pragma unroll
    for (int mt = 0; mt < 16; ++mt) {
        short8v a = *(const short8v*)(kpl + mt*256);
        f32x4 s = __builtin_amdgcn_mfma_f32_16x16x32_bf16(a, bq, z, 0, 0, 0);
        unsigned int* dst = Pu + (mt >> 1)*256 + (mt & 1)*128 + wbase;
        dst[0] = cvtpk(exp2f(s[0]), exp2f(s[1]));
        dst[1] = cvtpk(exp2f(s[2]), exp2f(s[3]));
    }
    f32x4 o = z;
    const ushortT* vpl = lds + 4112 + l15*264 + l4*8;
#pragma unroll
    for (int ks = 0; ks < 8; ++ks) {
        short8v bp = *(const short8v*)(Pw + ks*512 + l4*128 + l15*8);
        short8v av = *(const short8v*)(vpl + ks*32);
        o = __builtin_amdgcn_mfma_f32_16x16x32_bf16(av, bp, o, 0, 0, 0);
    }
    float rinv = 1.0f / __shfl(o[0], 48 + l15, 64);
    if (l4 < 3) {
        unsigned int* od = (unsigned int*)(obuf + (long)(row0 + l15)*96 + h*12 + l4*4);
        od[0] = cvtpk(o[0]*rinv, o[1]*rinv);
        od[1] = cvtpk(o[2]*rinv, o[3]*rinv);
    }
}

// ------- K5: out = o @ W0 via MFMA (W0^T bf16 frags from global) -------
__global__ __launch_bounds__(256) void k_out(const ushortT* __restrict__ obuf,
        const ushortT* __restrict__ w0T, float* __restrict__ out) {
    __shared__ ushortT ol[64*104];
    const int tid = threadIdx.x;
    const int r0 = blockIdx.x * 64;
    for (int i = tid; i < 768; i += 256) {
        int r = i / 12, sg = i % 12;
        *reinterpret_cast<uint4*>(&ol[r*104 + sg*8]) =
            *reinterpret_cast<const uint4*>(&obuf[(long)(r0 + r)*96 + sg*8]);
    }
    __syncthreads();
    const int lane = tid & 63, wv = tid >> 6;
    const int l15 = lane & 15, l4 = lane >> 4;
    short8v a[3];
#pragma unroll
    for (int kt = 0; kt < 3; ++kt)
        a[kt] = *(const short8v*)((const short*)ol + (wv*16 + l15)*104 + kt*32 + l4*8);
#pragma unroll
    for (int nt = 0; nt < 6; ++nt) {
        f32x4 acc = {0.f, 0.f, 0.f, 0.f};
#pragma unroll
        for (int kt = 0; kt < 3; ++kt) {
            short8v bw = *(const short8v*)((const short*)w0T + (nt*16 + l15)*96 + kt*32 + l4*8);
            acc = __builtin_amdgcn_mfma_f32_16x16x32_bf16(a[kt], bw, acc, 0, 0, 0);
        }
#pragma unroll
        for (int r = 0; r < 4; ++r)
            out[(long)(r0 + wv*16 + l4*4 + r)*96 + nt*16 + l15] = acc[r];
    }
}

extern "C" void kernel_launch(void* const* d_in, const int* in_sizes, int n_in,
                              void* d_out, int out_size, void* d_ws, size_t ws_size,
                              hipStream_t stream) {
    (void)in_sizes; (void)n_in; (void)out_size; (void)ws_size;
    const float* x    = (const float*)d_in[0];
    const float* Wqkv = (const float*)d_in[1];
    const float* W0   = (const float*)d_in[2];
    const float* E    = (const float*)d_in[3];
    const float* c0w  = (const float*)d_in[4];
    const float* c0b  = (const float*)d_in[5];
    const float* cspw = (const float*)d_in[6];
    const float* cspb = (const float*)d_in[7];
    const float* c1w  = (const float*)d_in[8];
    const float* c1b  = (const float*)d_in[9];
    float* out = (float*)d_out;
    float* ws  = (float*)d_ws;

    // layout (float offsets):
    // qkv16 @0 | wqT16 @4718592 | w0T16 @4732416 | w1c16 @4737024 | ET16 @4741632
    // XT16 @6838784 | a1p @9984512 (4,092,672 f padded) | a2_16 @14077184 (1.57M f)
    // part16 overlays @9984512..16275968 (a1p+a2 dead by k_ered) | obuf same
    // kp16 @16275968 | vp16 @16308736
    ushortT* qkv16  = (ushortT*)ws;
    ushortT* wqT16  = (ushortT*)(ws + 4718592);
    ushortT* w0T16  = (ushortT*)(ws + 4732416);
    ushortT* w1c16  = (ushortT*)(ws + 4737024);
    ushortT* ET16   = (ushortT*)(ws + 4741632);
    ushortT* XT16   = (ushortT*)(ws + 6838784);
    float* a1p      = ws + 9984512;
    ushortT* a2_16  = (ushortT*)(ws + 14077184);
    ushortT* part16 = (ushortT*)(ws + 9984512);
    ushortT* obuf   = (ushortT*)(ws + 9984512);
    ushortT* kp16   = (ushortT*)(ws + 16275968);
    ushortT* vp16   = (ushortT*)(ws + 16308736);

    k_front<<<dim3(2268), dim3(256), 0, stream>>>(x, c0w, c0b, E, Wqkv, W0, c1w,
                                                  a1p, ET16, wqT16, w0T16, w1c16);
    k_mid<<<dim3(1536), dim3(256), 0, stream>>>(x, wqT16, qkv16, a1p, cspw, cspb, a2_16);
    k_pw_gate<<<dim3(NROW/64), dim3(256), 0, stream>>>(a2_16, w1c16, c1b, x, qkv16, XT16);
    k_ered<<<dim3(256), dim3(512), 0, stream>>>(ET16, XT16, part16);
    k_ered_fin<<<dim3(384), dim3(256), 0, stream>>>(part16, kp16, vp16);
    k_attn<<<dim3((NROW/64)*NH), dim3(256), 0, stream>>>(qkv16, kp16, vp16, obuf);
    k_out<<<dim3(NROW/64), dim3(256), 0, stream>>>(obuf, w0T16, out);
}

// Round 16
// 126.989 us; speedup vs baseline: 1.0939x; 1.0939x over previous
//
#include <hip/hip_runtime.h>

#define HH_ 128
#define WW_ 128
#define LL_ (HH_*WW_)     // 16384
#define NH 8
#define DHD 12
#define KD 256
#define BB_ 2
#define NROW (BB_*LL_)    // 32768

typedef __attribute__((ext_vector_type(8))) short short8v;
typedef __attribute__((ext_vector_type(4))) float f32x4;
typedef unsigned short ushortT;

__device__ __forceinline__ float4 ld4(const float* p) {
    return *reinterpret_cast<const float4*>(p);
}
__device__ __forceinline__ unsigned int pk2(float a, float b) {
    unsigned int ua = __float_as_uint(a);
    unsigned int ub = __float_as_uint(b);
    ua = (ua + 0x7FFFu + ((ua >> 16) & 1u)) >> 16;
    ub = (ub + 0x7FFFu + ((ub >> 16) & 1u)) >> 16;
    return ua | (ub << 16);
}
__device__ __forceinline__ ushortT bf1(float a) {
    unsigned int u = __float_as_uint(a);
    return (ushortT)((u + 0x7FFFu + ((u >> 16) & 1u)) >> 16);
}
__device__ __forceinline__ float ubf(ushortT v) {
    return __uint_as_float(((unsigned int)v) << 16);
}
// single-instruction packed f32->bf16 (RNE), gfx950
__device__ __forceinline__ unsigned int cvtpk(float a, float b) {
    unsigned int r;
    asm("v_cvt_pk_bf16_f32 %0, %1, %2" : "=v"(r) : "v"(a), "v"(b));
    return r;
}
__device__ __forceinline__ float4 ubf4(uint2 t) {
    float4 r;
    r.x = ubf((ushortT)(t.x & 0xFFFF)); r.y = ubf((ushortT)(t.x >> 16));
    r.z = ubf((ushortT)(t.y & 0xFFFF)); r.w = ubf((ushortT)(t.y >> 16));
    return r;
}

// ======= K_FRONT: blocks [0,1024) = dw5 (bf16 a1); [1024,2048) = E->ET16;
//                  [2048,2228) = weight prep (wqT/w0T/w1c bf16) =======
__global__ __launch_bounds__(256) void k_front(const float* __restrict__ x,
        const float* __restrict__ c0w, const float* __restrict__ c0b,
        const float* __restrict__ E, const float* __restrict__ Wq,
        const float* __restrict__ W0, const float* __restrict__ w1,
        ushortT* __restrict__ a1_16, ushortT* __restrict__ ET,
        ushortT* __restrict__ wqT, ushortT* __restrict__ w0T,
        ushortT* __restrict__ w1c) {
    __shared__ __align__(16) float shf[2400];   // 9600B union
    const int tid = threadIdx.x;
    if (blockIdx.x < 1024) {
        // ---- dw5: depthwise 5x5, pad 2, channels-last, bf16 out ----
        float* wl = shf;   // [25][96]
        for (int i = tid; i < 25*96; i += 256) {
            int c = i / 25, t = i % 25;
            wl[t*96 + c] = c0w[i];
        }
        __syncthreads();
        const int c4 = (tid & 7)*4;
        const int px = tid >> 3;
        const int pix0 = blockIdx.x * 32;
        const int b = pix0 >> 14;
        const int y = (pix0 & 16383) >> 7;
        const int xx = (pix0 & 127) + px;
        float4 acc[3];
#pragma unroll
        for (int ch = 0; ch < 3; ++ch) { acc[ch].x=0.f; acc[ch].y=0.f; acc[ch].z=0.f; acc[ch].w=0.f; }
#pragma unroll
        for (int iy = 0; iy < 5; ++iy) {
            int y2 = y + iy - 2;
            if (y2 < 0 || y2 >= HH_) continue;
#pragma unroll
            for (int ix = 0; ix < 5; ++ix) {
                int x2 = xx + ix - 2;
                if (x2 < 0 || x2 >= WW_) continue;
                const float* src = x + ((b << 14) + y2*WW_ + x2)*96;
                const float* wt = &wl[(iy*5 + ix)*96];
#pragma unroll
                for (int ch = 0; ch < 3; ++ch) {
                    float4 xv = ld4(src + ch*32 + c4);
                    float4 wv = ld4(wt + ch*32 + c4);
                    acc[ch].x = fmaf(xv.x, wv.x, acc[ch].x);
                    acc[ch].y = fmaf(xv.y, wv.y, acc[ch].y);
                    acc[ch].z = fmaf(xv.z, wv.z, acc[ch].z);
                    acc[ch].w = fmaf(xv.w, wv.w, acc[ch].w);
                }
            }
        }
        ushortT* dst = a1_16 + (long)(pix0 + px)*96;
#pragma unroll
        for (int ch = 0; ch < 3; ++ch) {
            float4 bv = ld4(c0b + ch*32 + c4);
            unsigned int* d32 = (unsigned int*)(dst + ch*32 + c4);
            d32[0] = pk2(acc[ch].x + bv.x, acc[ch].y + bv.y);
            d32[1] = pk2(acc[ch].z + bv.z, acc[ch].w + bv.w);
        }
    } else if (blockIdx.x < 2048) {
        // ---- E -> ET16[kk][j] bf16 transposed ----
        ushortT* Tz = (ushortT*)shf;   // [64][66]
        const int bid = blockIdx.x - 1024;
        const int jt = bid >> 2, kt = bid & 3;
        const int j0 = jt * 64, kk0 = kt * 64;
        for (int i = tid; i < 64*16; i += 256) {
            int row = i >> 4, s4 = (i & 15) << 2;
            float4 e4 = ld4(&E[(long)(j0 + row)*256 + kk0 + s4]);
            Tz[(s4 + 0)*66 + row] = bf1(e4.x);
            Tz[(s4 + 1)*66 + row] = bf1(e4.y);
            Tz[(s4 + 2)*66 + row] = bf1(e4.z);
            Tz[(s4 + 3)*66 + row] = bf1(e4.w);
        }
        __syncthreads();
        unsigned int* Tu = (unsigned int*)Tz;
        for (int i = tid; i < 64*32; i += 256) {
            int kk = i >> 5, s = i & 31;
            ((unsigned int*)ET)[(((long)(kk0 + kk) << 14) + j0 >> 1) + s] = Tu[kk*33 + s];
        }
    } else {
        int i = (blockIdx.x - 2048)*256 + tid;
        if (i < 27648) {
            int n = i / 96, k = i % 96;
            wqT[n*96 + k] = bf1(Wq[k*288 + n]);
        } else if (i < 36864) {
            int j = i - 27648;
            int n = j / 96, k = j % 96;
            w0T[n*96 + k] = bf1(W0[k*96 + n]);
        } else if (i < 46080) {
            int j = i - 36864;
            w1c[j] = bf1(w1[j]);
        }
    }
}

// ======= K_MID: blocks [0,512) = qkv MFMA; [512,1536) = dw7 (bf16 in, bf16 a2) =======
__global__ __launch_bounds__(256) void k_mid(const float* __restrict__ x,
        const ushortT* __restrict__ wqT, ushortT* __restrict__ qkv16,
        const ushortT* __restrict__ a1_16, const float* __restrict__ cspw,
        const float* __restrict__ cspb, ushortT* __restrict__ a2_16) {
    __shared__ __align__(16) float shm[4704];   // 18816B union
    const int tid = threadIdx.x;
    if (blockIdx.x < 512) {
        // ---- qkv16 = bf16(x @ Wqkv) via MFMA ----
        ushortT* xb = (ushortT*)shm;   // [64][104]
        const int r0w = blockIdx.x * 64;
        for (int i = tid; i < 64*48; i += 256) {
            int r = i / 48, cp = i % 48;
            const float* sp = x + (long)(r0w + r)*96 + cp*2;
            ((unsigned int*)xb)[r*52 + cp] = pk2(sp[0], sp[1]);
        }
        __syncthreads();
        const int lane = tid & 63, wv = tid >> 6;
        const int l15 = lane & 15, l4 = lane >> 4;
        short8v bx[3];
#pragma unroll
        for (int kt = 0; kt < 3; ++kt)
            bx[kt] = *(const short8v*)((const short*)xb + (wv*16 + l15)*104 + kt*32 + l4*8);
#pragma unroll 2
        for (int mt = 0; mt < 18; ++mt) {
            f32x4 acc = {0.f, 0.f, 0.f, 0.f};
#pragma unroll
            for (int kt = 0; kt < 3; ++kt) {
                short8v a = *(const short8v*)((const short*)wqT + (mt*16 + l15)*96 + kt*32 + l4*8);
                acc = __builtin_amdgcn_mfma_f32_16x16x32_bf16(a, bx[kt], acc, 0, 0, 0);
            }
            unsigned int* q32 = (unsigned int*)(qkv16 + (long)(r0w + wv*16 + l15)*288 + mt*16 + l4*4);
            q32[0] = pk2(acc[0], acc[1]);
            q32[1] = pk2(acc[2], acc[3]);
        }
    } else {
        // ---- dw7: depthwise 7x7 dil 3 pad 9, reads bf16 a1, writes bf16 a2 ----
        float* wl = shm;   // [49][96]
        for (int i = tid; i < 49*96; i += 256) {
            int c = i / 49, t = i % 49;
            wl[t*96 + c] = cspw[i];
        }
        __syncthreads();
        const int c4 = (tid & 7)*4;
        const int px = tid >> 3;
        const int pix0 = (blockIdx.x - 512) * 32;
        const int b = pix0 >> 14;
        const int y = (pix0 & 16383) >> 7;
        const int xx = (pix0 & 127) + px;
        float4 acc[3];
#pragma unroll
        for (int ch = 0; ch < 3; ++ch) { acc[ch].x=0.f; acc[ch].y=0.f; acc[ch].z=0.f; acc[ch].w=0.f; }
#pragma unroll
        for (int iy = 0; iy < 7; ++iy) {
            int y2 = y + iy*3 - 9;
            if (y2 < 0 || y2 >= HH_) continue;
#pragma unroll
            for (int ix = 0; ix < 7; ++ix) {
                int x2 = xx + ix*3 - 9;
                if (x2 < 0 || x2 >= WW_) continue;
                const ushortT* src = a1_16 + ((long)(b << 14) + y2*WW_ + x2)*96 + c4;
                const float* wt = &wl[(iy*7 + ix)*96 + c4];
#pragma unroll
                for (int ch = 0; ch < 3; ++ch) {
                    float4 xv = ubf4(*reinterpret_cast<const uint2*>(src + ch*32));
                    float4 wv = ld4(wt + ch*32);
                    acc[ch].x = fmaf(xv.x, wv.x, acc[ch].x);
                    acc[ch].y = fmaf(xv.y, wv.y, acc[ch].y);
                    acc[ch].z = fmaf(xv.z, wv.z, acc[ch].z);
                    acc[ch].w = fmaf(xv.w, wv.w, acc[ch].w);
                }
            }
        }
        ushortT* dst = a2_16 + (long)(pix0 + px)*96;
#pragma unroll
        for (int ch = 0; ch < 3; ++ch) {
            float4 bv = ld4(cspb + ch*32 + c4);
            unsigned int* d32 = (unsigned int*)(dst + ch*32 + c4);
            d32[0] = pk2(acc[ch].x + bv.x, acc[ch].y + bv.y);
            d32[1] = pk2(acc[ch].z + bv.z, acc[ch].w + bv.w);
        }
    }
}

// ------- K2c: fused a3 = a2@w1^T + b1 (MFMA); vf = x*a3*v; writes BOTH halves
// of XT[b][cc 192][j] (cc<96 = k transposed, cc>=96 = vf transposed). 64 rows/blk -------
__global__ __launch_bounds__(256) void k_pw_gate(const ushortT* __restrict__ a2_16,
        const ushortT* __restrict__ w1c, const float* __restrict__ b1,
        const float* __restrict__ xin, const ushortT* __restrict__ qkv16,
        ushortT* __restrict__ XT) {
    __shared__ ushortT ab[64*104];     // 13312B
    __shared__ ushortT ktile[96*66];   // 12672B
    __shared__ ushortT vtile[96*66];   // 12672B
    const int tid = threadIdx.x;
    const int r0 = blockIdx.x * 64;
    const int b = r0 >> 14, j0 = r0 & 16383;
    const unsigned int* a2u = (const unsigned int*)a2_16;
    for (int i = tid; i < 64*48; i += 256) {
        int r = i / 48, cp = i % 48;
        ((unsigned int*)ab)[r*52 + cp] = a2u[(long)(r0 + r)*48 + cp];
    }
    const unsigned int* q32 = (const unsigned int*)qkv16;
    for (int i = tid; i < 64*48; i += 256) {
        int row = i / 48, cp = i % 48;
        unsigned int kk2 = q32[(long)(r0 + row)*144 + 48 + cp];
        ktile[(2*cp + 0)*66 + row] = (ushortT)(kk2 & 0xFFFF);
        ktile[(2*cp + 1)*66 + row] = (ushortT)(kk2 >> 16);
    }
    __syncthreads();
    const int lane = tid & 63, wv = tid >> 6;
    const int l15 = lane & 15, l4 = lane >> 4;
    const int row = r0 + wv*16 + l15;
    const int jloc = wv*16 + l15;
    short8v bx[3];
#pragma unroll
    for (int kt = 0; kt < 3; ++kt)
        bx[kt] = *(const short8v*)((const short*)ab + (wv*16 + l15)*104 + kt*32 + l4*8);
#pragma unroll
    for (int mt = 0; mt < 6; ++mt) {
        f32x4 acc = {0.f, 0.f, 0.f, 0.f};
#pragma unroll
        for (int kt = 0; kt < 3; ++kt) {
            short8v a = *(const short8v*)((const short*)w1c + (mt*16 + l15)*96 + kt*32 + l4*8);
            acc = __builtin_amdgcn_mfma_f32_16x16x32_bf16(a, bx[kt], acc, 0, 0, 0);
        }
        const int c0 = mt*16 + l4*4;
        float4 b4 = ld4(&b1[c0]);
        float4 x4 = ld4(&xin[(long)row*96 + c0]);
        uint2 vv = *reinterpret_cast<const uint2*>(qkv16 + (long)row*288 + 192 + c0);
        float v0 = ubf((ushortT)(vv.x & 0xFFFF)), v1 = ubf((ushortT)(vv.x >> 16));
        float v2 = ubf((ushortT)(vv.y & 0xFFFF)), v3 = ubf((ushortT)(vv.y >> 16));
        vtile[(c0 + 0)*66 + jloc] = bf1(x4.x * v0 * (acc[0] + b4.x));
        vtile[(c0 + 1)*66 + jloc] = bf1(x4.y * v1 * (acc[1] + b4.y));
        vtile[(c0 + 2)*66 + jloc] = bf1(x4.z * v2 * (acc[2] + b4.z));
        vtile[(c0 + 3)*66 + jloc] = bf1(x4.w * v3 * (acc[3] + b4.w));
    }
    __syncthreads();
    unsigned int* XTu = (unsigned int*)XT;
    unsigned int* ku = (unsigned int*)ktile;
    unsigned int* vu = (unsigned int*)vtile;
    for (int i = tid; i < 96*32; i += 256) {
        int cc = i >> 5, s = i & 31;
        XTu[((((long)b*192 + cc) << 14) + j0 >> 1) + s] = ku[cc*33 + s];
    }
    for (int i = tid; i < 96*32; i += 256) {
        int cc = i >> 5, s = i & 31;
        XTu[((((long)b*192 + 96 + cc) << 14) + j0 >> 1) + s] = vu[cc*33 + s];
    }
}

// ------- K3a: E-reduction as MFMA split-K GEMM (no LDS) -------
__global__ __launch_bounds__(512, 2) void k_ered(const ushortT* __restrict__ ET,
        const ushortT* __restrict__ XT, ushortT* __restrict__ part16) {
    const int tid = threadIdx.x;
    const int lane = tid & 63, wv = tid >> 6;
    const int l15 = lane & 15, l4 = lane >> 4;
    const int mtg = wv & 3, nth = wv >> 2;
    const int b  = blockIdx.x >> 7;
    const int jc = blockIdx.x & 127;
    const int j0 = jc * 128;
    f32x4 acc[4][6];
#pragma unroll
    for (int mi = 0; mi < 4; ++mi)
#pragma unroll
        for (int ni = 0; ni < 6; ++ni)
            acc[mi][ni] = (f32x4){0.f, 0.f, 0.f, 0.f};
    const ushortT* Ab = ET + ((long)(mtg*64 + l15) << 14) + j0 + l4*8;
    const ushortT* Bb = XT + (((long)b*192 + nth*96 + l15) << 14) + j0 + l4*8;
#pragma unroll
    for (int ks = 0; ks < 4; ++ks) {
        short8v a[4], bx[6];
#pragma unroll
        for (int mi = 0; mi < 4; ++mi)
            a[mi] = *(const short8v*)(Ab + ((long)mi << 18) + ks*32);
#pragma unroll
        for (int ni = 0; ni < 6; ++ni)
            bx[ni] = *(const short8v*)(Bb + ((long)ni << 18) + ks*32);
#pragma unroll
        for (int mi = 0; mi < 4; ++mi)
#pragma unroll
            for (int ni = 0; ni < 6; ++ni)
                acc[mi][ni] = __builtin_amdgcn_mfma_f32_16x16x32_bf16(a[mi], bx[ni], acc[mi][ni], 0, 0, 0);
    }
    const long base = (long)(b*128 + jc)*49152;
#pragma unroll
    for (int mi = 0; mi < 4; ++mi) {
        int kkb = (mtg*4 + mi)*16 + l4*4;
#pragma unroll
        for (int ni = 0; ni < 6; ++ni) {
            int cc = (nth*6 + ni)*16 + l15;
#pragma unroll
            for (int r = 0; r < 4; ++r)
                part16[base + (long)(kkb + r)*192 + cc] = bf1(acc[mi][ni][r]);
        }
    }
}

// ------- K3b: reduce partials -> bf16 kp16[b][h][kk][16] (scaled by 1/sqrt(12)*log2e,
// pads 0), vp16[b][h][16][256] (row 12 = ONES for MFMA row-sum, 13..15 = 0) -------
__global__ __launch_bounds__(256) void k_ered_fin(const ushortT* __restrict__ part16,
        ushortT* __restrict__ kp16, ushortT* __restrict__ vp16) {
    const int idx = blockIdx.x*256 + threadIdx.x;  // 2*2*256*96 = 98304
    const int c  = idx % 96;
    const int kk = (idx / 96) % 256;
    const int m  = (idx / (96*256)) % 2;
    const int b  = idx / (96*256*2);
    float s = 0.f;
    long off = ((long)(b*128)*256 + kk)*192 + m*96 + c;
    for (int jc = 0; jc < 128; ++jc) {
        s += ubf(part16[off]);
        off += 49152;
    }
    const int h = c / DHD, d = c % DHD;
    if (m == 0) {
        kp16[((b*NH + h)*256 + kk)*16 + d] = bf1(s * 0.4164701998f);
        if (d < 4) kp16[((b*NH + h)*256 + kk)*16 + 12 + d] = 0;
    } else {
        vp16[((b*NH + h)*16 + d)*256 + kk] = bf1(s);
        if (d < 4)
            vp16[((b*NH + h)*16 + 12 + d)*256 + kk] = (d == 0) ? (ushortT)0x3F80 : (ushortT)0;
    }
}

// ------- K4 v3: flash-style. Block = 64 rows x ONE head; kp/vp staged in LDS -------
__global__ __launch_bounds__(256, 4) void k_attn(const ushortT* __restrict__ qkv16,
        const ushortT* __restrict__ kp16, const ushortT* __restrict__ vp16,
        ushortT* __restrict__ obuf) {
    __shared__ ushortT lds[24720];
    const int tid = threadIdx.x;
    const int lane = tid & 63, wv = tid >> 6;
    const int l15 = lane & 15, l4 = lane >> 4;
    const int bid = blockIdx.x;
    const int r0 = (bid >> 3) * 64;
    const int h = bid & 7;
    const int b = r0 >> 14;
    {
        const uint4* ksrc = (const uint4*)(kp16 + ((long)(b*NH + h) << 12));
        uint4* kdst = (uint4*)lds;
        kdst[tid] = ksrc[tid];
        kdst[256 + tid] = ksrc[256 + tid];
        const uint4* vsrc = (const uint4*)(vp16 + ((long)(b*NH + h) << 12));
        uint4* vdst = (uint4*)(lds + 4112);
        int r1 = tid >> 5, s1 = tid & 31;
        vdst[r1*33 + s1] = vsrc[tid];
        int j2 = tid + 256;
        int r2 = j2 >> 5, s2 = j2 & 31;
        vdst[r2*33 + s2] = vsrc[j2];
        if (tid < 2) ((uint4*)(lds + 4096))[tid] = (uint4){0u, 0u, 0u, 0u};
    }
    __syncthreads();
    ushortT* Pw = lds + 8336 + wv*4096;
    unsigned int* Pu = (unsigned int*)Pw;
    const int wbase = (l4 >> 1)*64 + l15*4 + (l4 & 1)*2;
    const f32x4 z = {0.f, 0.f, 0.f, 0.f};
    const int row0 = r0 + wv*16;
    short8v bq = {0, 0, 0, 0, 0, 0, 0, 0};
    {
        unsigned int* bq32 = (unsigned int*)&bq;
        const ushortT* qp = qkv16 + (long)(row0 + l15)*288 + h*12;
        if (l4 == 0) {
            uint2 t0 = *reinterpret_cast<const uint2*>(qp);
            uint2 t1 = *reinterpret_cast<const uint2*>(qp + 4);
            bq32[0] = t0.x; bq32[1] = t0.y; bq32[2] = t1.x; bq32[3] = t1.y;
        } else if (l4 == 1) {
            uint2 t0 = *reinterpret_cast<const uint2*>(qp + 8);
            bq32[0] = t0.x; bq32[1] = t0.y;
        }
    }
    const ushortT* kpl = lds + l15*16 + l4*8;
#pragma unroll
    for (int mt = 0; mt < 16; ++mt) {
        short8v a = *(const short8v*)(kpl + mt*256);
        f32x4 s = __builtin_amdgcn_mfma_f32_16x16x32_bf16(a, bq, z, 0, 0, 0);
        unsigned int* dst = Pu + (mt >> 1)*256 + (mt & 1)*128 + wbase;
        dst[0] = cvtpk(exp2f(s[0]), exp2f(s[1]));
        dst[1] = cvtpk(exp2f(s[2]), exp2f(s[3]));
    }
    f32x4 o = z;
    const ushortT* vpl = lds + 4112 + l15*264 + l4*8;
#pragma unroll
    for (int ks = 0; ks < 8; ++ks) {
        short8v bp = *(const short8v*)(Pw + ks*512 + l4*128 + l15*8);
        short8v av = *(const short8v*)(vpl + ks*32);
        o = __builtin_amdgcn_mfma_f32_16x16x32_bf16(av, bp, o, 0, 0, 0);
    }
    float rinv = 1.0f / __shfl(o[0], 48 + l15, 64);
    if (l4 < 3) {
        unsigned int* od = (unsigned int*)(obuf + (long)(row0 + l15)*96 + h*12 + l4*4);
        od[0] = cvtpk(o[0]*rinv, o[1]*rinv);
        od[1] = cvtpk(o[2]*rinv, o[3]*rinv);
    }
}

// ------- K5: out = o @ W0 via MFMA (W0^T bf16 frags from global) -------
__global__ __launch_bounds__(256) void k_out(const ushortT* __restrict__ obuf,
        const ushortT* __restrict__ w0T, float* __restrict__ out) {
    __shared__ ushortT ol[64*104];
    const int tid = threadIdx.x;
    const int r0 = blockIdx.x * 64;
    for (int i = tid; i < 768; i += 256) {
        int r = i / 12, sg = i % 12;
        *reinterpret_cast<uint4*>(&ol[r*104 + sg*8]) =
            *reinterpret_cast<const uint4*>(&obuf[(long)(r0 + r)*96 + sg*8]);
    }
    __syncthreads();
    const int lane = tid & 63, wv = tid >> 6;
    const int l15 = lane & 15, l4 = lane >> 4;
    short8v a[3];
#pragma unroll
    for (int kt = 0; kt < 3; ++kt)
        a[kt] = *(const short8v*)((const short*)ol + (wv*16 + l15)*104 + kt*32 + l4*8);
#pragma unroll
    for (int nt = 0; nt < 6; ++nt) {
        f32x4 acc = {0.f, 0.f, 0.f, 0.f};
#pragma unroll
        for (int kt = 0; kt < 3; ++kt) {
            short8v bw = *(const short8v*)((const short*)w0T + (nt*16 + l15)*96 + kt*32 + l4*8);
            acc = __builtin_amdgcn_mfma_f32_16x16x32_bf16(a[kt], bw, acc, 0, 0, 0);
        }
#pragma unroll
        for (int r = 0; r < 4; ++r)
            out[(long)(r0 + wv*16 + l4*4 + r)*96 + nt*16 + l15] = acc[r];
    }
}

extern "C" void kernel_launch(void* const* d_in, const int* in_sizes, int n_in,
                              void* d_out, int out_size, void* d_ws, size_t ws_size,
                              hipStream_t stream) {
    (void)in_sizes; (void)n_in; (void)out_size; (void)ws_size;
    const float* x    = (const float*)d_in[0];
    const float* Wqkv = (const float*)d_in[1];
    const float* W0   = (const float*)d_in[2];
    const float* E    = (const float*)d_in[3];
    const float* c0w  = (const float*)d_in[4];
    const float* c0b  = (const float*)d_in[5];
    const float* cspw = (const float*)d_in[6];
    const float* cspb = (const float*)d_in[7];
    const float* c1w  = (const float*)d_in[8];
    const float* c1b  = (const float*)d_in[9];
    float* out = (float*)d_out;
    float* ws  = (float*)d_ws;

    // layout (float offsets):
    // qkv16 @0 | wqT16 @4718592 | w0T16 @4732416 | w1c16 @4737024 | ET16 @4741632
    // XT16 @6838784 | a1_16 @9984512 (1.57M f as ushort) | a2_16 @11557376 (1.57M f)
    // part16 overlays @9984512..16275968 (a1/a2 dead by k_ered) | obuf same region
    // kp16 @16275968 | vp16 @16308736
    ushortT* qkv16  = (ushortT*)ws;
    ushortT* wqT16  = (ushortT*)(ws + 4718592);
    ushortT* w0T16  = (ushortT*)(ws + 4732416);
    ushortT* w1c16  = (ushortT*)(ws + 4737024);
    ushortT* ET16   = (ushortT*)(ws + 4741632);
    ushortT* XT16   = (ushortT*)(ws + 6838784);
    ushortT* a1_16  = (ushortT*)(ws + 9984512);
    ushortT* a2_16  = (ushortT*)(ws + 11557376);
    ushortT* part16 = (ushortT*)(ws + 9984512);
    ushortT* obuf   = (ushortT*)(ws + 9984512);
    ushortT* kp16   = (ushortT*)(ws + 16275968);
    ushortT* vp16   = (ushortT*)(ws + 16308736);

    k_front<<<dim3(2228), dim3(256), 0, stream>>>(x, c0w, c0b, E, Wqkv, W0, c1w,
                                                  a1_16, ET16, wqT16, w0T16, w1c16);
    k_mid<<<dim3(1536), dim3(256), 0, stream>>>(x, wqT16, qkv16, a1_16, cspw, cspb, a2_16);
    k_pw_gate<<<dim3(NROW/64), dim3(256), 0, stream>>>(a2_16, w1c16, c1b, x, qkv16, XT16);
    k_ered<<<dim3(256), dim3(512), 0, stream>>>(ET16, XT16, part16);
    k_ered_fin<<<dim3(384), dim3(256), 0, stream>>>(part16, kp16, vp16);
    k_attn<<<dim3((NROW/64)*NH), dim3(256), 0, stream>>>(qkv16, kp16, vp16, obuf);
    k_out<<<dim3(NROW/64), dim3(256), 0, stream>>>(obuf, w0T16, out);
}